// Round 1
// baseline (85.105 us; speedup 1.0000x reference)
//
#include <hip/hip_runtime.h>
#include <hip/hip_cooperative_groups.h>

namespace cg = cooperative_groups;

#define T_HOR 5
#define MAXIT 100

// One thread per batch element. Two decoupled 2-state subsystems per element.
// Grid-wide convergence decision per iteration to exactly replicate the
// reference's while_loop (global max |u_new - u| > EPS).
__global__ __launch_bounds__(256)
void mpc_iter_kernel(const float* __restrict__ x_init,
                     const float* __restrict__ xd,
                     float* __restrict__ out,
                     int* __restrict__ flags)
{
    cg::grid_group grid = cg::this_grid();
    const int b = blockIdx.x * 256 + threadIdx.x;

    // x order: [p1, p2, v1, v2]
    const float xi0 = x_init[4*b+0];
    const float xi1 = x_init[4*b+1];
    const float xi2 = x_init[4*b+2];
    const float xi3 = x_init[4*b+3];
    const float SQ01 = 0.31622776601683794f; // sqrt(0.1)
    // px = -sqrt(w) * xd, w = [1,1,0.1,0.1]
    const float pc_p1 = -xd[4*b+0];
    const float pc_p2 = -xd[4*b+1];
    const float pc_v1 = -SQ01 * xd[4*b+2];
    const float pc_v2 = -SQ01 * xd[4*b+3];

    // Batch-independent Riccati gain schedule (constant-folds at compile time):
    //   subsystem: A=[[1,0.1],[0,0.75]], B=[[0,0],[0.5,-0.5]], Cx=diag(1,0.1), Cu=0.1 I
    //   s = 0.25*Vvv ; Quu=[[.1+s,-s],[-s,.1+s]] ; d = 0.1*(0.1+2s)
    //   kk = -Quu^{-1} qu -> coeffs c0=(0.1+s)/d, c1=s/d
    //   Qux=[[g,h],[-g,-h]], g=0.5*Vpv, h=0.05*Vpv+0.375*Vvv
    //   K = [[-g',-h'],[g',h']], g'=g/(0.1+2s), h'=h/(0.1+2s)
    //   V' = Qxx + Qxu K   (exact cancellation of Quu terms)
    float c0[T_HOR], c1[T_HOR], gp[T_HOR], hp[T_HOR];
    {
        float Vpp = 0.f, Vpv = 0.f, Vvv = 0.f;
        #pragma unroll
        for (int t = T_HOR-1; t >= 0; --t) {
            float s  = 0.25f * Vvv;
            float tw = 0.1f + 2.f*s;
            float dd = 0.1f * tw;
            c0[t] = (0.1f + s) / dd;
            c1[t] = s / dd;
            float g = 0.5f * Vpv;
            float h = 0.05f * Vpv + 0.375f * Vvv;
            float inv = 1.f / tw;
            gp[t] = g * inv;
            hp[t] = h * inv;
            float nVpp = 1.0f + Vpp - 2.f*g*gp[t];
            float nVpv = 0.1f*Vpp + 0.75f*Vpv - 2.f*g*hp[t];
            float nVvv = 0.1f + 0.01f*Vpp + 0.15f*Vpv + 0.5625f*Vvv - 2.f*h*hp[t];
            Vpp = nVpp; Vpv = nVpv; Vvv = nVvv;
        }
    }

    // controls, init 0: subsystem1 -> (ua1,ub1)=u[:,0],u[:,1]; subsystem2 -> u[:,2],u[:,3]
    float ua1[T_HOR] = {0,0,0,0,0}, ub1[T_HOR] = {0,0,0,0,0};
    float ua2[T_HOR] = {0,0,0,0,0}, ub2[T_HOR] = {0,0,0,0,0};

    for (int it = 0; it < MAXIT; ++it) {
        // ---- rollout: states x_0..x_{T-1}
        float xp1[T_HOR], xv1[T_HOR], xp2[T_HOR], xv2[T_HOR];
        xp1[0] = xi0; xp2[0] = xi1; xv1[0] = xi2; xv2[0] = xi3;
        #pragma unroll
        for (int t = 0; t < T_HOR-1; ++t) {
            xp1[t+1] = xp1[t] + 0.1f*xv1[t];
            xv1[t+1] = 0.75f*xv1[t] + 0.5f*(ua1[t]-ub1[t]);
            xp2[t+1] = xp2[t] + 0.1f*xv2[t];
            xv2[t+1] = 0.75f*xv2[t] + 0.5f*(ua2[t]-ub2[t]);
        }

        // ---- backward affine pass: kk_t and v recursion (v_new = qx + K^T qu)
        float ka1[T_HOR], kb1[T_HOR], ka2[T_HOR], kb2[T_HOR];
        float v1p = 0.f, v1v = 0.f, v2p = 0.f, v2v = 0.f;
        #pragma unroll
        for (int t = T_HOR-1; t >= 0; --t) {
            // qu = cu + B^T v ; cu = 0.01 + 0.1*u
            float qa = 0.01f + 0.1f*ua1[t] + 0.5f*v1v;
            float qb = 0.01f + 0.1f*ub1[t] - 0.5f*v1v;
            ka1[t] = -(c0[t]*qa + c1[t]*qb);
            kb1[t] = -(c1[t]*qa + c0[t]*qb);
            float qxp = (pc_p1 + xp1[t]) + v1p;                    // cx_p = px + 1.0*p
            float qxv = (pc_v1 + 0.1f*xv1[t]) + 0.1f*v1p + 0.75f*v1v; // cx_v = px_v + 0.1*v
            float dq = qa - qb;
            v1p = qxp - gp[t]*dq;
            v1v = qxv - hp[t]*dq;

            float qa2 = 0.01f + 0.1f*ua2[t] + 0.5f*v2v;
            float qb2 = 0.01f + 0.1f*ub2[t] - 0.5f*v2v;
            ka2[t] = -(c0[t]*qa2 + c1[t]*qb2);
            kb2[t] = -(c1[t]*qa2 + c0[t]*qb2);
            float qxp2 = (pc_p2 + xp2[t]) + v2p;
            float qxv2 = (pc_v2 + 0.1f*xv2[t]) + 0.1f*v2p + 0.75f*v2v;
            float dq2 = qa2 - qb2;
            v2p = qxp2 - gp[t]*dq2;
            v2v = qxv2 - hp[t]*dq2;
        }

        // ---- forward pass with clip; track max |du|
        float delta = 0.f;
        float d1p = 0.f, d1v = 0.f, d2p = 0.f, d2v = 0.f;
        #pragma unroll
        for (int t = 0; t < T_HOR; ++t) {
            float phi1 = gp[t]*d1p + hp[t]*d1v;
            float na = fminf(fmaxf(ua1[t] + (ka1[t] - phi1), 0.f), 1.f);
            float nb = fminf(fmaxf(ub1[t] + (kb1[t] + phi1), 0.f), 1.f);
            float dua = na - ua1[t], dub = nb - ub1[t];
            delta = fmaxf(delta, fmaxf(fabsf(dua), fabsf(dub)));
            float n1p = d1p + 0.1f*d1v;
            float n1v = 0.75f*d1v + 0.5f*(dua - dub);
            d1p = n1p; d1v = n1v;
            ua1[t] = na; ub1[t] = nb;

            float phi2 = gp[t]*d2p + hp[t]*d2v;
            float na2 = fminf(fmaxf(ua2[t] + (ka2[t] - phi2), 0.f), 1.f);
            float nb2 = fminf(fmaxf(ub2[t] + (kb2[t] + phi2), 0.f), 1.f);
            float dua2 = na2 - ua2[t], dub2 = nb2 - ub2[t];
            delta = fmaxf(delta, fmaxf(fabsf(dua2), fabsf(dub2)));
            float n2p = d2p + 0.1f*d2v;
            float n2v = 0.75f*d2v + 0.5f*(dua2 - dub2);
            d2p = n2p; d2v = n2v;
            ua2[t] = na2; ub2[t] = nb2;
        }

        // ---- global convergence decision (exact reference semantics)
        int nc = (delta > 0.01f) ? 1 : 0;
        int bnc = __syncthreads_or(nc);
        if (threadIdx.x == 0 && bnc) {
            __hip_atomic_fetch_or(&flags[it], 1, __ATOMIC_RELEASE, __HIP_MEMORY_SCOPE_AGENT);
        }
        grid.sync();
        int f = __hip_atomic_load(&flags[it], __ATOMIC_ACQUIRE, __HIP_MEMORY_SCOPE_AGENT);
        if (f == 0) break;   // uniform across the grid -> no divergent sync
    }

    out[4*b+0] = ua1[0];
    out[4*b+1] = ub1[0];
    out[4*b+2] = ua2[0];
    out[4*b+3] = ub2[0];
}

extern "C" void kernel_launch(void* const* d_in, const int* in_sizes, int n_in,
                              void* d_out, int out_size, void* d_ws, size_t ws_size,
                              hipStream_t stream) {
    const float* x_init = (const float*)d_in[0];
    const float* xd     = (const float*)d_in[1];
    float* out          = (float*)d_out;
    int* flags          = (int*)d_ws;

    const int B = in_sizes[0] / 4;          // 65536
    hipMemsetAsync(d_ws, 0, MAXIT * sizeof(int), stream);

    void* args[] = { (void*)&x_init, (void*)&xd, (void*)&out, (void*)&flags };
    dim3 grid(B / 256), block(256);
    hipLaunchCooperativeKernel((const void*)mpc_iter_kernel, grid, block, args, 0, stream);
}

// Round 2
// 64.021 us; speedup vs baseline: 1.3293x; 1.3293x over previous
//
#include <hip/hip_runtime.h>
#include <hip/hip_cooperative_groups.h>

namespace cg = cooperative_groups;

#define T_HOR 5
#define MAXIT 100
#define KGRP  16
#define NGRP  ((MAXIT + KGRP - 1) / KGRP)   // 7
#define EPSC  0.01f

// One LQR sweep for one batch element (two decoupled 2-state subsystems).
// Returns max |du| over all controls/timesteps. All arrays statically indexed
// inside unrolled T-loops -> fully register-resident.
__device__ __forceinline__ float iter_once(
    const float (&c0)[T_HOR], const float (&c1)[T_HOR],
    const float (&gp)[T_HOR], const float (&hp)[T_HOR],
    float xi0, float xi1, float xi2, float xi3,
    float pc_p1, float pc_v1, float pc_p2, float pc_v2,
    float (&ua1)[T_HOR], float (&ub1)[T_HOR],
    float (&ua2)[T_HOR], float (&ub2)[T_HOR])
{
    // rollout
    float xp1[T_HOR], xv1[T_HOR], xp2[T_HOR], xv2[T_HOR];
    xp1[0] = xi0; xp2[0] = xi1; xv1[0] = xi2; xv2[0] = xi3;
    #pragma unroll
    for (int t = 0; t < T_HOR-1; ++t) {
        xp1[t+1] = xp1[t] + 0.1f*xv1[t];
        xv1[t+1] = 0.75f*xv1[t] + 0.5f*(ua1[t]-ub1[t]);
        xp2[t+1] = xp2[t] + 0.1f*xv2[t];
        xv2[t+1] = 0.75f*xv2[t] + 0.5f*(ua2[t]-ub2[t]);
    }

    // backward affine pass
    float ka1[T_HOR], kb1[T_HOR], ka2[T_HOR], kb2[T_HOR];
    float v1p = 0.f, v1v = 0.f, v2p = 0.f, v2v = 0.f;
    #pragma unroll
    for (int t = T_HOR-1; t >= 0; --t) {
        float qa = 0.01f + 0.1f*ua1[t] + 0.5f*v1v;
        float qb = 0.01f + 0.1f*ub1[t] - 0.5f*v1v;
        ka1[t] = -(c0[t]*qa + c1[t]*qb);
        kb1[t] = -(c1[t]*qa + c0[t]*qb);
        float qxp = (pc_p1 + xp1[t]) + v1p;
        float qxv = (pc_v1 + 0.1f*xv1[t]) + 0.1f*v1p + 0.75f*v1v;
        float dq = qa - qb;
        v1p = qxp - gp[t]*dq;
        v1v = qxv - hp[t]*dq;

        float qa2 = 0.01f + 0.1f*ua2[t] + 0.5f*v2v;
        float qb2 = 0.01f + 0.1f*ub2[t] - 0.5f*v2v;
        ka2[t] = -(c0[t]*qa2 + c1[t]*qb2);
        kb2[t] = -(c1[t]*qa2 + c0[t]*qb2);
        float qxp2 = (pc_p2 + xp2[t]) + v2p;
        float qxv2 = (pc_v2 + 0.1f*xv2[t]) + 0.1f*v2p + 0.75f*v2v;
        float dq2 = qa2 - qb2;
        v2p = qxp2 - gp[t]*dq2;
        v2v = qxv2 - hp[t]*dq2;
    }

    // forward pass with clip
    float delta = 0.f;
    float d1p = 0.f, d1v = 0.f, d2p = 0.f, d2v = 0.f;
    #pragma unroll
    for (int t = 0; t < T_HOR; ++t) {
        float phi1 = gp[t]*d1p + hp[t]*d1v;
        float na = fminf(fmaxf(ua1[t] + (ka1[t] - phi1), 0.f), 1.f);
        float nb = fminf(fmaxf(ub1[t] + (kb1[t] + phi1), 0.f), 1.f);
        float dua = na - ua1[t], dub = nb - ub1[t];
        delta = fmaxf(delta, fmaxf(fabsf(dua), fabsf(dub)));
        float n1p = d1p + 0.1f*d1v;
        float n1v = 0.75f*d1v + 0.5f*(dua - dub);
        d1p = n1p; d1v = n1v;
        ua1[t] = na; ub1[t] = nb;

        float phi2 = gp[t]*d2p + hp[t]*d2v;
        float na2 = fminf(fmaxf(ua2[t] + (ka2[t] - phi2), 0.f), 1.f);
        float nb2 = fminf(fmaxf(ub2[t] + (kb2[t] + phi2), 0.f), 1.f);
        float dua2 = na2 - ua2[t], dub2 = nb2 - ub2[t];
        delta = fmaxf(delta, fmaxf(fabsf(dua2), fabsf(dub2)));
        float n2p = d2p + 0.1f*d2v;
        float n2v = 0.75f*d2v + 0.5f*(dua2 - dub2);
        d2p = n2p; d2v = n2v;
        ua2[t] = na2; ub2[t] = nb2;
    }
    return delta;
}

__global__ __launch_bounds__(256)
void mpc_iter_kernel(const float4* __restrict__ x_init,
                     const float4* __restrict__ xd,
                     float4* __restrict__ out,
                     int* __restrict__ gmask)
{
    cg::grid_group grid = cg::this_grid();
    const int b = blockIdx.x * 256 + threadIdx.x;

    const float4 xi  = x_init[b];   // [p1, p2, v1, v2]
    const float4 xdv = xd[b];
    const float SQ01 = 0.31622776601683794f;
    const float pc_p1 = -xdv.x;
    const float pc_p2 = -xdv.y;
    const float pc_v1 = -SQ01 * xdv.z;
    const float pc_v2 = -SQ01 * xdv.w;

    // Batch-independent Riccati gain schedule (constant-folds at compile time)
    float c0[T_HOR], c1[T_HOR], gp[T_HOR], hp[T_HOR];
    {
        float Vpp = 0.f, Vpv = 0.f, Vvv = 0.f;
        #pragma unroll
        for (int t = T_HOR-1; t >= 0; --t) {
            float s  = 0.25f * Vvv;
            float tw = 0.1f + 2.f*s;
            float dd = 0.1f * tw;
            c0[t] = (0.1f + s) / dd;
            c1[t] = s / dd;
            float g = 0.5f * Vpv;
            float h = 0.05f * Vpv + 0.375f * Vvv;
            float inv = 1.f / tw;
            gp[t] = g * inv;
            hp[t] = h * inv;
            float nVpp = 1.0f + Vpp - 2.f*g*gp[t];
            float nVpv = 0.1f*Vpp + 0.75f*Vpv - 2.f*g*hp[t];
            float nVvv = 0.1f + 0.01f*Vpp + 0.15f*Vpv + 0.5625f*Vvv - 2.f*h*hp[t];
            Vpp = nVpp; Vpv = nVpv; Vvv = nVvv;
        }
    }

    float ua1[T_HOR] = {0,0,0,0,0}, ub1[T_HOR] = {0,0,0,0,0};
    float ua2[T_HOR] = {0,0,0,0,0}, ub2[T_HOR] = {0,0,0,0,0};

    int it_base = 0;
    for (int g = 0; g < NGRP; ++g) {
        // checkpoint controls at group start
        float ck0[T_HOR], ck1[T_HOR], ck2[T_HOR], ck3[T_HOR];
        #pragma unroll
        for (int t = 0; t < T_HOR; ++t) {
            ck0[t] = ua1[t]; ck1[t] = ub1[t]; ck2[t] = ua2[t]; ck3[t] = ub2[t];
        }

        const int gl = (MAXIT - it_base < KGRP) ? (MAXIT - it_base) : KGRP;
        unsigned mask = 0;
        for (int j = 0; j < gl; ++j) {
            float delta = iter_once(c0, c1, gp, hp, xi.x, xi.y, xi.z, xi.w,
                                    pc_p1, pc_v1, pc_p2, pc_v2,
                                    ua1, ub1, ua2, ub2);
            mask |= (delta > EPSC ? 1u : 0u) << j;
        }

        int m = __syncthreads_or((int)mask);
        if (threadIdx.x == 0 && m) {
            __hip_atomic_fetch_or(&gmask[g], m, __ATOMIC_RELEASE, __HIP_MEMORY_SCOPE_AGENT);
        }
        grid.sync();
        int gm = __hip_atomic_load(&gmask[g], __ATOMIC_ACQUIRE, __HIP_MEMORY_SCOPE_AGENT);

        // first iteration (0-based within group) where ALL elements had delta<=EPS
        int j0 = __ffs(~(unsigned)gm) - 1;   // bits >= gl are 0 in gm, so j0<=gl
        if (j0 < gl) {
            // stop fired at global iteration it_base+j0+1: restore + replay
            #pragma unroll
            for (int t = 0; t < T_HOR; ++t) {
                ua1[t] = ck0[t]; ub1[t] = ck1[t]; ua2[t] = ck2[t]; ub2[t] = ck3[t];
            }
            for (int j = 0; j <= j0; ++j) {
                iter_once(c0, c1, gp, hp, xi.x, xi.y, xi.z, xi.w,
                          pc_p1, pc_v1, pc_p2, pc_v2,
                          ua1, ub1, ua2, ub2);
            }
            break;
        }
        it_base += KGRP;
        if (it_base >= MAXIT) break;   // hit iteration cap: output u(MAXIT)
    }

    out[b] = make_float4(ua1[0], ub1[0], ua2[0], ub2[0]);
}

extern "C" void kernel_launch(void* const* d_in, const int* in_sizes, int n_in,
                              void* d_out, int out_size, void* d_ws, size_t ws_size,
                              hipStream_t stream) {
    const float4* x_init = (const float4*)d_in[0];
    const float4* xd     = (const float4*)d_in[1];
    float4* out          = (float4*)d_out;
    int* gmask           = (int*)d_ws;

    const int B = in_sizes[0] / 4;          // 65536
    hipMemsetAsync(d_ws, 0, NGRP * sizeof(int), stream);

    void* args[] = { (void*)&x_init, (void*)&xd, (void*)&out, (void*)&gmask };
    dim3 grid(B / 256), block(256);
    hipLaunchCooperativeKernel((const void*)mpc_iter_kernel, grid, block, args, 0, stream);
}